// Round 1
// baseline (1062.122 us; speedup 1.0000x reference)
//
#include <hip/hip_runtime.h>
#include <math.h>

#define M_ROWS 131072
#define D_DIM 256
#define NCODES 1024
#define QELEMS (M_ROWS * D_DIM)  // 33554432

// workspace layout (bytes)
#define WS_EMBEDT   0u          // 1024*256*4 = 1048576
#define WS_ENORM    1048576u    // 4096
#define WS_PARTIALS 1052672u    // 131072*8*8 = 8388608
#define WS_COUNTS   9441280u    // 4096
#define WS_LOSSP    9445376u    // 8192*4 = 32768
#define WS_IDX      9478144u    // 131072*4 = 524288
// total: 10002432 bytes

// ---------------------------------------------------------------------------
// Transpose embed [256][1024] -> embedT [1024][256]; per-code squared norms.
__global__ __launch_bounds__(256) void k_tnorm(const float* __restrict__ embed,
                                               float* __restrict__ embedT,
                                               float* __restrict__ enorm) {
  int c = blockIdx.x;   // code 0..1023
  int t = threadIdx.x;  // k 0..255
  float v = embed[t * NCODES + c];
  embedT[c * D_DIM + t] = v;
  float s = v * v;
  for (int off = 32; off > 0; off >>= 1) s += __shfl_down(s, off, 64);
  __shared__ float red[4];
  if ((t & 63) == 0) red[t >> 6] = s;
  __syncthreads();
  if (t == 0) enorm[c] = red[0] + red[1] + red[2] + red[3];
}

// ---------------------------------------------------------------------------
// Tiled fp32 GEMM (128 rows x 128 codes per block, K=256) with fused
// per-row argmin epilogue over d = ||e||^2 - 2*x.e  (||x||^2 constant/row).
__global__ __launch_bounds__(256, 2) void k_dist(const float* __restrict__ A,
                                                 const float* __restrict__ B,
                                                 const float* __restrict__ enorm,
                                                 float2* __restrict__ partials) {
  __shared__ float As[32][128];  // [k][row], 16 KB
  __shared__ float Bs[32][128];  // [k][col], 16 KB
  int bx = blockIdx.x;
  int ct = bx & 7;        // col tile 0..7
  int rt = bx >> 3;       // row tile 0..1023
  int rowBase = rt * 128;
  int colBase = ct * 128;
  int t = threadIdx.x;
  int tx = t & 15;        // col group
  int ty = t >> 4;        // row group

  float acc[8][8];
#pragma unroll
  for (int i = 0; i < 8; ++i)
#pragma unroll
    for (int j = 0; j < 8; ++j) acc[i][j] = 0.f;

  for (int kc = 0; kc < 256; kc += 32) {
    // Stage A chunk: 128 rows x 32 k (transposed into LDS)
#pragma unroll
    for (int u = 0; u < 4; ++u) {
      int id = t + 256 * u;  // 0..1023
      int r = id >> 3;       // row in tile
      int kq = id & 7;       // float4 index in k-chunk
      float4 v = *(const float4*)(A + (size_t)(rowBase + r) * D_DIM + kc + kq * 4);
      As[kq * 4 + 0][r] = v.x;
      As[kq * 4 + 1][r] = v.y;
      As[kq * 4 + 2][r] = v.z;
      As[kq * 4 + 3][r] = v.w;
    }
    // Stage B chunk: 32 k x 128 cols (row-major, contiguous)
#pragma unroll
    for (int u = 0; u < 4; ++u) {
      int id = t + 256 * u;
      int k = id >> 5;       // 0..31
      int cq = id & 31;      // float4 col index
      float4 v = *(const float4*)(B + (size_t)(kc + k) * NCODES + colBase + cq * 4);
      *(float4*)&Bs[k][cq * 4] = v;
    }
    __syncthreads();
#pragma unroll
    for (int k = 0; k < 32; ++k) {
      float a[8], b[8];
      *(float4*)&a[0] = *(const float4*)&As[k][ty * 4];
      *(float4*)&a[4] = *(const float4*)&As[k][64 + ty * 4];
      *(float4*)&b[0] = *(const float4*)&Bs[k][tx * 4];
      *(float4*)&b[4] = *(const float4*)&Bs[k][64 + tx * 4];
#pragma unroll
      for (int i = 0; i < 8; ++i)
#pragma unroll
        for (int j = 0; j < 8; ++j) acc[i][j] = fmaf(a[i], b[j], acc[i][j]);
    }
    __syncthreads();
  }

  // Epilogue: per-row argmin of (enorm[c] - 2*s) across this 128-col tile.
  float en[8];
#pragma unroll
  for (int j = 0; j < 4; ++j) {
    en[j] = enorm[colBase + tx * 4 + j];
    en[4 + j] = enorm[colBase + 64 + tx * 4 + j];
  }
#pragma unroll
  for (int s = 0; s < 8; ++s) {
    float best = 3.0e38f;
    int bidx = 0;
#pragma unroll
    for (int jj = 0; jj < 8; ++jj) {
      int c = colBase + (jj < 4 ? tx * 4 + jj : 64 + tx * 4 + (jj - 4));
      float d = fmaf(-2.f, acc[s][jj], en[jj]);
      if (d < best) { best = d; bidx = c; }  // jj ascending => first-min wins
    }
    // reduce across the 16 tx lanes sharing this row group (contiguous lanes)
    for (int off = 1; off < 16; off <<= 1) {
      float ob = __shfl_xor(best, off, 64);
      int oi = __shfl_xor(bidx, off, 64);
      if (ob < best || (ob == best && oi < bidx)) { best = ob; bidx = oi; }
    }
    if (tx == 0) {
      int grow = rowBase + (s < 4 ? ty * 4 + s : 64 + ty * 4 + (s - 4));
      partials[(size_t)grow * 8 + ct] = make_float2(best, (float)bidx);
    }
  }
}

// ---------------------------------------------------------------------------
// Reduce 8 column-tile partials per row -> final index; histogram.
__global__ __launch_bounds__(256) void k_argmin(const float2* __restrict__ partials,
                                                float* __restrict__ out_ind,
                                                int* __restrict__ idxbuf,
                                                int* __restrict__ counts) {
  int row = blockIdx.x * 256 + threadIdx.x;
  float best = 3.0e38f;
  int bi = 0;
#pragma unroll
  for (int tp = 0; tp < 8; ++tp) {  // ascending tile order: strict < keeps first
    float2 p = partials[(size_t)row * 8 + tp];
    int c = (int)p.y;
    if (p.x < best || (p.x == best && c < bi)) { best = p.x; bi = c; }
  }
  out_ind[row] = (float)bi;
  idxbuf[row] = bi;
  atomicAdd(&counts[bi], 1);
}

// ---------------------------------------------------------------------------
// Gather codebook rows (coalesced via embedT), straight-through output,
// per-block loss partial sums.
__global__ __launch_bounds__(256) void k_quant(const float* __restrict__ x,
                                               const float* __restrict__ embedT,
                                               const int* __restrict__ idxbuf,
                                               float* __restrict__ outq,
                                               float* __restrict__ lossPart) {
  int b = blockIdx.x;
  int t = threadIdx.x;
  int rlocal = t >> 6;  // wave id 0..3
  int lane = t & 63;
  float s = 0.f;
#pragma unroll
  for (int ri = 0; ri < 4; ++ri) {
    int row = b * 16 + ri * 4 + rlocal;
    int idx = idxbuf[row];
    float4 xv = *(const float4*)(x + (size_t)row * D_DIM + lane * 4);
    float4 qv = *(const float4*)(embedT + (size_t)idx * D_DIM + lane * 4);
    float dx = qv.x - xv.x, dy = qv.y - xv.y, dz = qv.z - xv.z, dw = qv.w - xv.w;
    float4 o = make_float4(xv.x + dx, xv.y + dy, xv.z + dz, xv.w + dw);
    *(float4*)(outq + (size_t)row * D_DIM + lane * 4) = o;
    s = fmaf(dx, dx, s); s = fmaf(dy, dy, s); s = fmaf(dz, dz, s); s = fmaf(dw, dw, s);
  }
  for (int off = 32; off > 0; off >>= 1) s += __shfl_down(s, off, 64);
  __shared__ float red[4];
  if (lane == 0) red[rlocal] = s;
  __syncthreads();
  if (t == 0) lossPart[b] = red[0] + red[1] + red[2] + red[3];
}

// ---------------------------------------------------------------------------
// Final scalars: loss mean (double accumulate) + perplexity from histogram.
__global__ __launch_bounds__(1024) void k_final(const int* __restrict__ counts,
                                                const float* __restrict__ lossPart,
                                                float* __restrict__ out_scalars) {
  int t = threadIdx.x;
  double ls = 0.0;
#pragma unroll
  for (int u = 0; u < 8; ++u) ls += (double)lossPart[t * 8 + u];
  float p = (float)counts[t] * (1.0f / (float)M_ROWS);
  float ent = p * logf(p + 1e-10f);
  double lred = ls;
  float ered = ent;
  for (int off = 32; off > 0; off >>= 1) {
    lred += __shfl_down(lred, off, 64);
    ered += __shfl_down(ered, off, 64);
  }
  __shared__ double lsh[16];
  __shared__ float esh[16];
  int w = t >> 6;
  if ((t & 63) == 0) { lsh[w] = lred; esh[w] = ered; }
  __syncthreads();
  if (t == 0) {
    double L = 0.0;
    float E = 0.f;
    for (int i = 0; i < 16; ++i) { L += lsh[i]; E += esh[i]; }
    out_scalars[0] = (float)(L / (double)QELEMS);  // loss
    out_scalars[1] = expf(-E);                     // perplexity
  }
}

// ---------------------------------------------------------------------------
extern "C" void kernel_launch(void* const* d_in, const int* in_sizes, int n_in,
                              void* d_out, int out_size, void* d_ws, size_t ws_size,
                              hipStream_t stream) {
  const float* inputs = (const float*)d_in[0];  // [131072,256]
  const float* embed = (const float*)d_in[1];   // [256,1024]
  float* out = (float*)d_out;
  char* ws = (char*)d_ws;
  float* embedT = (float*)(ws + WS_EMBEDT);
  float* enorm = (float*)(ws + WS_ENORM);
  float2* partials = (float2*)(ws + WS_PARTIALS);
  int* counts = (int*)(ws + WS_COUNTS);
  float* lossPart = (float*)(ws + WS_LOSSP);
  int* idxbuf = (int*)(ws + WS_IDX);

  hipMemsetAsync(counts, 0, NCODES * sizeof(int), stream);
  k_tnorm<<<NCODES, 256, 0, stream>>>(embed, embedT, enorm);
  k_dist<<<8192, 256, 0, stream>>>(inputs, embed, enorm, partials);
  k_argmin<<<M_ROWS / 256, 256, 0, stream>>>(partials, out + QELEMS + 2, idxbuf, counts);
  k_quant<<<8192, 256, 0, stream>>>(inputs, embedT, idxbuf, out, lossPart);
  k_final<<<1, 1024, 0, stream>>>(counts, lossPart, out + QELEMS);
}

// Round 2
// 972.463 us; speedup vs baseline: 1.0922x; 1.0922x over previous
//
#include <hip/hip_runtime.h>
#include <math.h>

#define M_ROWS 131072
#define D_DIM 256
#define NCODES 1024
#define QELEMS (M_ROWS * D_DIM)  // 33554432

typedef __attribute__((ext_vector_type(4))) short short4v;
typedef __attribute__((ext_vector_type(8))) short short8v;
typedef __attribute__((ext_vector_type(4))) float f32x4;

// workspace layout (bytes)
#define WS_EMBEDT   0u          // 1024*256*4   = 1048576
#define WS_EHI      1048576u    // 1024*256*2   = 524288
#define WS_ELO      1572864u    // 524288
#define WS_ENORM    2097152u    // 4096
#define WS_PART     2101248u    // 8*131072*16  = 16777216
#define WS_IDX2     18878464u   // 131072*8     = 1048576
#define WS_COUNTS   19927040u   // 4096
#define WS_LOSSP    19931136u   // 8192*4       = 32768
// total ~19.97 MB

__device__ inline unsigned short f2bf(float x) {
  union { float f; unsigned u; } c; c.f = x;
  unsigned u = c.u;
  u += 0x7FFFu + ((u >> 16) & 1u);  // round-to-nearest-even
  return (unsigned short)(u >> 16);
}
__device__ inline float bf2f(unsigned short h) {
  union { float f; unsigned u; } c; c.u = ((unsigned)h) << 16;
  return c.f;
}
// merge candidate top-2 (o0,oi0,o1,oi1) into running top-2; tie -> lower index
__device__ inline void merge2(float& b0, int& i0, float& b1, int& i1,
                              float o0, int oi0, float o1, int oi1) {
  if (o0 < b0 || (o0 == b0 && oi0 < i0)) {
    if (b0 < o1 || (b0 == o1 && i0 < oi1)) { b1 = b0; i1 = i0; }
    else { b1 = o1; i1 = oi1; }
    b0 = o0; i0 = oi0;
  } else {
    if (o0 < b1 || (o0 == b1 && oi0 < i1)) { b1 = o0; i1 = oi0; }
  }
}

// ---------------------------------------------------------------------------
// Prep: embedT fp32 (for gather/rescore), bf16 hi/lo split of embed^T, norms.
__global__ __launch_bounds__(256) void k_prep(const float* __restrict__ embed,
                                              float* __restrict__ embedT,
                                              unsigned short* __restrict__ ehiT,
                                              unsigned short* __restrict__ eloT,
                                              float* __restrict__ enorm) {
  int c = blockIdx.x, t = threadIdx.x;
  float v = embed[t * NCODES + c];
  embedT[c * D_DIM + t] = v;
  unsigned short hi = f2bf(v);
  ehiT[c * D_DIM + t] = hi;
  eloT[c * D_DIM + t] = f2bf(v - bf2f(hi));
  float s = v * v;
  for (int off = 32; off > 0; off >>= 1) s += __shfl_down(s, off, 64);
  __shared__ float red[4];
  if ((t & 63) == 0) red[t >> 6] = s;
  __syncthreads();
  if (t == 0) enorm[c] = red[0] + red[1] + red[2] + red[3];
}

// ---------------------------------------------------------------------------
// MFMA split-bf16 distance GEMM with fused per-row top-2 epilogue.
// Block: 128 rows x 128 codes, 4 waves each 64x64 (4x4 grid of 16x16x32 MFMA).
// acc = xhi.ehi + xhi.elo + xlo.ehi  (fp32 accumulate) ~ fp32-accurate ranking.
__global__ __launch_bounds__(256, 3) void k_dist(const float* __restrict__ A,
                                                 const unsigned short* __restrict__ ehiT,
                                                 const unsigned short* __restrict__ eloT,
                                                 const float* __restrict__ enorm,
                                                 float4* __restrict__ partials) {
  // XOR-swizzled [128 rows][32 k] bf16 tiles: 16B unit u of row r stored at
  // u^(r&3) -> conflict-free ds_read_b128 frag reads, 16B aligned, no pad.
  __shared__ unsigned short sAhi[128 * 32];
  __shared__ unsigned short sAlo[128 * 32];
  __shared__ unsigned short sBhi[128 * 32];
  __shared__ unsigned short sBlo[128 * 32];
  __shared__ float4 sRed[2][128];

  int bx = blockIdx.x;
  int ct = bx & 7, rt = bx >> 3;
  int rowBase = rt << 7, colBase = ct << 7;
  int t = threadIdx.x;
  int w = t >> 6, lane = t & 63;
  int wr = w >> 1, wc = w & 1;       // wave tile coords in 2x2
  int lm = lane & 15, quad = lane >> 4;

  int sr = t >> 1;                   // staging row/code 0..127
  int skh = (t & 1) << 4;            // staging k-half 0/16

  f32x4 acc[4][4];
#pragma unroll
  for (int i = 0; i < 4; ++i)
#pragma unroll
    for (int j = 0; j < 4; ++j) acc[i][j] = (f32x4){0.f, 0.f, 0.f, 0.f};

  // frag LDS offsets (ushort units); k0 = quad*8 -> unit = quad
  int aoff[4], boff[4];
#pragma unroll
  for (int ti = 0; ti < 4; ++ti) {
    int r = (wr << 6) + (ti << 4) + lm;
    aoff[ti] = r * 32 + ((quad ^ (r & 3)) << 3);
    int n = (wc << 6) + (ti << 4) + lm;
    boff[ti] = n * 32 + ((quad ^ (n & 3)) << 3);
  }

  const float* Arow = A + (size_t)(rowBase + sr) * D_DIM + skh;
  const unsigned short* Bhirow = ehiT + (size_t)(colBase + sr) * D_DIM + skh;
  const unsigned short* Blorow = eloT + (size_t)(colBase + sr) * D_DIM + skh;

  for (int kc = 0; kc < D_DIM; kc += 32) {
    // stage A: load fp32, split to bf16 hi/lo
#pragma unroll
    for (int u = 0; u < 4; ++u) {
      float4 v = *(const float4*)(Arow + kc + (u << 2));
      int koff = skh + (u << 2);
      int dst = sr * 32 + (((koff >> 3) ^ (sr & 3)) << 3) + (koff & 7);
      unsigned short h0 = f2bf(v.x), h1 = f2bf(v.y), h2 = f2bf(v.z), h3 = f2bf(v.w);
      short4v hv = {(short)h0, (short)h1, (short)h2, (short)h3};
      *(short4v*)&sAhi[dst] = hv;
      short4v lv = {(short)f2bf(v.x - bf2f(h0)), (short)f2bf(v.y - bf2f(h1)),
                    (short)f2bf(v.z - bf2f(h2)), (short)f2bf(v.w - bf2f(h3))};
      *(short4v*)&sAlo[dst] = lv;
    }
    // stage B: precomputed bf16, straight 16B copies
#pragma unroll
    for (int h = 0; h < 2; ++h) {
      int koff = skh + (h << 3);
      int dst = sr * 32 + (((koff >> 3) ^ (sr & 3)) << 3);
      *(uint4*)&sBhi[dst] = *(const uint4*)(Bhirow + kc + (h << 3));
      *(uint4*)&sBlo[dst] = *(const uint4*)(Blorow + kc + (h << 3));
    }
    __syncthreads();

    short8v ahi[4], alo[4], bhi[4], blo[4];
#pragma unroll
    for (int i = 0; i < 4; ++i) {
      ahi[i] = *(const short8v*)&sAhi[aoff[i]];
      bhi[i] = *(const short8v*)&sBhi[boff[i]];
      blo[i] = *(const short8v*)&sBlo[boff[i]];
      alo[i] = *(const short8v*)&sAlo[aoff[i]];
    }
#pragma unroll
    for (int i = 0; i < 4; ++i)
#pragma unroll
      for (int j = 0; j < 4; ++j)
        acc[i][j] = __builtin_amdgcn_mfma_f32_16x16x32_bf16(ahi[i], bhi[j], acc[i][j], 0, 0, 0);
#pragma unroll
    for (int i = 0; i < 4; ++i)
#pragma unroll
      for (int j = 0; j < 4; ++j)
        acc[i][j] = __builtin_amdgcn_mfma_f32_16x16x32_bf16(ahi[i], blo[j], acc[i][j], 0, 0, 0);
#pragma unroll
    for (int i = 0; i < 4; ++i)
#pragma unroll
      for (int j = 0; j < 4; ++j)
        acc[i][j] = __builtin_amdgcn_mfma_f32_16x16x32_bf16(alo[i], bhi[j], acc[i][j], 0, 0, 0);
    __syncthreads();
  }

  // Epilogue: d = ||e||^2 - 2*x.e ; per-row top-2 across this block's 128 cols.
  // C/D layout (16x16x32): col = lane&15, row = quad*4 + reg.
  float enC[4]; int cidx[4];
#pragma unroll
  for (int j = 0; j < 4; ++j) {
    cidx[j] = colBase + (wc << 6) + (j << 4) + lm;
    enC[j] = enorm[cidx[j]];
  }
#pragma unroll
  for (int ti = 0; ti < 4; ++ti) {
#pragma unroll
    for (int reg = 0; reg < 4; ++reg) {
      float b0 = 3.0e38f, b1 = 3.0e38f;
      int i0 = 0x7fffffff, i1 = 0x7fffffff;
#pragma unroll
      for (int j = 0; j < 4; ++j) {
        float v = fmaf(-2.f, acc[ti][j][reg], enC[j]);
        int c = cidx[j];
        if (v < b0 || (v == b0 && c < i0)) { b1 = b0; i1 = i0; b0 = v; i0 = c; }
        else if (v < b1 || (v == b1 && c < i1)) { b1 = v; i1 = c; }
      }
      // butterfly over the 16 lanes of this quad (rows match across them)
      for (int m = 1; m < 16; m <<= 1) {
        float o0 = __shfl_xor(b0, m, 64); int oi0 = __shfl_xor(i0, m, 64);
        float o1 = __shfl_xor(b1, m, 64); int oi1 = __shfl_xor(i1, m, 64);
        merge2(b0, i0, b1, i1, o0, oi0, o1, oi1);
      }
      if (lm == 0) {
        int rloc = (wr << 6) + (ti << 4) + (quad << 2) + reg;
        sRed[wc][rloc] = make_float4(b0, (float)i0, b1, (float)i1);
      }
    }
  }
  __syncthreads();
  if (t < 128) {
    float4 p = sRed[0][t];
    float b0 = p.x; int i0 = (int)p.y; float b1 = p.z; int i1 = (int)p.w;
    float4 q = sRed[1][t];
    merge2(b0, i0, b1, i1, q.x, (int)q.y, q.z, (int)q.w);
    partials[(size_t)ct * M_ROWS + rowBase + t] = make_float4(b0, (float)i0, b1, (float)i1);
  }
}

// ---------------------------------------------------------------------------
// Merge 8 col-tile top-2s -> global top-2 candidate indices per row.
__global__ __launch_bounds__(256) void k_argmin(const float4* __restrict__ partials,
                                                int2* __restrict__ idx2) {
  int row = blockIdx.x * 256 + threadIdx.x;
  float b0 = 3.0e38f, b1 = 3.0e38f;
  int i0 = 0x7fffffff, i1 = 0x7fffffff;
#pragma unroll
  for (int tp = 0; tp < 8; ++tp) {
    float4 p = partials[(size_t)tp * M_ROWS + row];
    merge2(b0, i0, b1, i1, p.x, (int)p.y, p.z, (int)p.w);
  }
  idx2[row] = make_int2(i0, i1);
}

// ---------------------------------------------------------------------------
// Exact fp32 rescore of top-2, final index, quantize + STE, loss, histogram.
__global__ __launch_bounds__(256) void k_quant(const float* __restrict__ x,
                                               const float* __restrict__ embedT,
                                               const int2* __restrict__ idx2,
                                               float* __restrict__ outq,
                                               float* __restrict__ out_ind,
                                               int* __restrict__ counts,
                                               float* __restrict__ lossPart) {
  int b = blockIdx.x, t = threadIdx.x;
  int rl = t >> 6, lane = t & 63;
  float lsum = 0.f;
  __shared__ float red[4];
#pragma unroll
  for (int ri = 0; ri < 4; ++ri) {
    int row = b * 16 + ri * 4 + rl;
    int2 cc = idx2[row];
    float4 xv = *(const float4*)(x + (size_t)row * D_DIM + (lane << 2));
    float4 q0 = *(const float4*)(embedT + (size_t)cc.x * D_DIM + (lane << 2));
    float4 q1 = *(const float4*)(embedT + (size_t)cc.y * D_DIM + (lane << 2));
    float a0 = q0.x - xv.x, a1 = q0.y - xv.y, a2 = q0.z - xv.z, a3 = q0.w - xv.w;
    float c0 = q1.x - xv.x, c1 = q1.y - xv.y, c2 = q1.z - xv.z, c3 = q1.w - xv.w;
    float d0 = fmaf(a0, a0, fmaf(a1, a1, fmaf(a2, a2, a3 * a3)));
    float d1 = fmaf(c0, c0, fmaf(c1, c1, fmaf(c2, c2, c3 * c3)));
    for (int m = 1; m < 64; m <<= 1) {
      d0 += __shfl_xor(d0, m, 64);
      d1 += __shfl_xor(d1, m, 64);
    }
    bool sel = (d1 < d0) || (d1 == d0 && cc.y < cc.x);
    int widx = sel ? cc.y : cc.x;
    float4 qv;
    qv.x = sel ? q1.x : q0.x; qv.y = sel ? q1.y : q0.y;
    qv.z = sel ? q1.z : q0.z; qv.w = sel ? q1.w : q0.w;
    float4 o = make_float4(xv.x + (qv.x - xv.x), xv.y + (qv.y - xv.y),
                           xv.z + (qv.z - xv.z), xv.w + (qv.w - xv.w));
    *(float4*)(outq + (size_t)row * D_DIM + (lane << 2)) = o;
    lsum += sel ? d1 : d0;  // identical across lanes; lane0's copy is used
    if (lane == 0) {
      out_ind[row] = (float)widx;
      atomicAdd(&counts[widx], 1);
    }
  }
  if (lane == 0) red[rl] = lsum;
  __syncthreads();
  if (t == 0) lossPart[b] = red[0] + red[1] + red[2] + red[3];
}

// ---------------------------------------------------------------------------
__global__ __launch_bounds__(1024) void k_final(const int* __restrict__ counts,
                                                const float* __restrict__ lossPart,
                                                float* __restrict__ out_scalars) {
  int t = threadIdx.x;
  double ls = 0.0;
#pragma unroll
  for (int u = 0; u < 8; ++u) ls += (double)lossPart[t * 8 + u];
  float p = (float)counts[t] * (1.0f / (float)M_ROWS);
  float ent = p * logf(p + 1e-10f);
  double lred = ls;
  float ered = ent;
  for (int off = 32; off > 0; off >>= 1) {
    lred += __shfl_down(lred, off, 64);
    ered += __shfl_down(ered, off, 64);
  }
  __shared__ double lsh[16];
  __shared__ float esh[16];
  int w = t >> 6;
  if ((t & 63) == 0) { lsh[w] = lred; esh[w] = ered; }
  __syncthreads();
  if (t == 0) {
    double L = 0.0;
    float E = 0.f;
    for (int i = 0; i < 16; ++i) { L += lsh[i]; E += esh[i]; }
    out_scalars[0] = (float)(L / (double)QELEMS);
    out_scalars[1] = expf(-E);
  }
}

// ---------------------------------------------------------------------------
extern "C" void kernel_launch(void* const* d_in, const int* in_sizes, int n_in,
                              void* d_out, int out_size, void* d_ws, size_t ws_size,
                              hipStream_t stream) {
  const float* inputs = (const float*)d_in[0];  // [131072,256]
  const float* embed = (const float*)d_in[1];   // [256,1024]
  float* out = (float*)d_out;
  char* ws = (char*)d_ws;
  float* embedT = (float*)(ws + WS_EMBEDT);
  unsigned short* ehiT = (unsigned short*)(ws + WS_EHI);
  unsigned short* eloT = (unsigned short*)(ws + WS_ELO);
  float* enorm = (float*)(ws + WS_ENORM);
  float4* partials = (float4*)(ws + WS_PART);
  int2* idx2 = (int2*)(ws + WS_IDX2);
  int* counts = (int*)(ws + WS_COUNTS);
  float* lossPart = (float*)(ws + WS_LOSSP);

  hipMemsetAsync(counts, 0, NCODES * sizeof(int), stream);
  k_prep<<<NCODES, 256, 0, stream>>>(embed, embedT, ehiT, eloT, enorm);
  k_dist<<<8192, 256, 0, stream>>>(inputs, ehiT, eloT, enorm, partials);
  k_argmin<<<M_ROWS / 256, 256, 0, stream>>>(partials, idx2);
  k_quant<<<8192, 256, 0, stream>>>(inputs, embedT, idx2, out, out + QELEMS + 2,
                                    counts, lossPart);
  k_final<<<1, 1024, 0, stream>>>(counts, lossPart, out + QELEMS);
}

// Round 3
// 924.327 us; speedup vs baseline: 1.1491x; 1.0521x over previous
//
#include <hip/hip_runtime.h>
#include <math.h>

#define M_ROWS 131072
#define D_DIM 256
#define NCODES 1024
#define QELEMS (M_ROWS * D_DIM)  // 33554432

typedef __attribute__((ext_vector_type(8))) short short8v;
typedef __attribute__((ext_vector_type(4))) float f32x4;
typedef unsigned short ushort_t;

// workspace layout (bytes)
#define WS_EMBEDT 0u          // 1024*256*4 = 1048576
#define WS_B1     1048576u    // 524288 (bf16 hi of embed^T; tiled in fast path, plain in slow)
#define WS_B2     1572864u    // 524288 (bf16 lo)
#define WS_ENORM  2097152u    // 4096
#define WS_PART   2101248u    // 8*131072*16 = 16777216
#define WS_IDX2   18878464u   // 1048576
#define WS_COUNTS 19927040u   // 4096
#define WS_LOSSP  19931136u   // 32768  -> slow-path total 19963904
#define WS_XHI    19963904u   // 67108864 (tiled+swizzled bf16-hi of inputs)
#define WS_XLO    87072768u   // 67108864
#define WS_FAST_TOTAL 154181632u

typedef unsigned int u32_g __attribute__((address_space(1)));
typedef unsigned int u32_l __attribute__((address_space(3)));
__device__ inline void gll16(const void* g, void* l) {
  // async global->LDS DMA, 16B/lane; LDS dest = uniform base + lane*16
  __builtin_amdgcn_global_load_lds((const u32_g*)g, (u32_l*)l, 16, 0, 0);
}

// truncation bf16 split helpers (v_perm packs two hi-halves in 1 instr)
__device__ inline unsigned pack2(float x, float y) {
  return __builtin_amdgcn_perm(__float_as_uint(y), __float_as_uint(x), 0x07060302u);
}
__device__ inline float rem1(float x) {
  return x - __uint_as_float(__float_as_uint(x) & 0xFFFF0000u);
}
__device__ inline void split8(float4 a, float4 b, uint4* hi, uint4* lo) {
  *hi = make_uint4(pack2(a.x, a.y), pack2(a.z, a.w), pack2(b.x, b.y), pack2(b.z, b.w));
  *lo = make_uint4(pack2(rem1(a.x), rem1(a.y)), pack2(rem1(a.z), rem1(a.w)),
                   pack2(rem1(b.x), rem1(b.y)), pack2(rem1(b.z), rem1(b.w)));
}

// merge candidate top-2 into running top-2; tie -> lower index
__device__ inline void merge2(float& b0, int& i0, float& b1, int& i1,
                              float o0, int oi0, float o1, int oi1) {
  if (o0 < b0 || (o0 == b0 && oi0 < i0)) {
    if (b0 < o1 || (b0 == o1 && i0 < oi1)) { b1 = b0; i1 = i0; }
    else { b1 = o1; i1 = oi1; }
    b0 = o0; i0 = oi0;
  } else {
    if (o0 < b1 || (o0 == b1 && oi0 < i1)) { b1 = o0; i1 = oi0; }
  }
}

// ---------------------------------------------------------------------------
// Prep: embedT fp32 (gather/rescore), bf16 hi/lo of embed^T (tiled-swizzled in
// fast mode, plain [code][k] in slow mode), per-code norms.
__global__ __launch_bounds__(256) void k_prep(const float* __restrict__ embed,
                                              float* __restrict__ embedT,
                                              ushort_t* __restrict__ b1,
                                              ushort_t* __restrict__ b2,
                                              float* __restrict__ enorm, int fast) {
  int c = blockIdx.x, t = threadIdx.x;  // c = code, t = k
  float v = embed[t * NCODES + c];
  embedT[c * D_DIM + t] = v;
  unsigned bits = __float_as_uint(v);
  ushort_t hi = (ushort_t)(bits >> 16);
  ushort_t lo = (ushort_t)(__float_as_uint(rem1(v)) >> 16);
  if (fast) {
    // tile (ct, kc): [128 codes][32 k], 16B unit u of code cl stored at u^(cl&3)
    int ct = c >> 7, cl = c & 127, kc = t >> 5, u = (t >> 3) & 3, j = t & 7;
    size_t off = (size_t)(ct * 8 + kc) * 4096 + cl * 32 + ((u ^ (cl & 3)) << 3) + j;
    b1[off] = hi; b2[off] = lo;
  } else {
    b1[c * D_DIM + t] = hi;
    b2[c * D_DIM + t] = lo;
  }
  float s = v * v;
  for (int off = 32; off > 0; off >>= 1) s += __shfl_down(s, off, 64);
  __shared__ float red[4];
  if ((t & 63) == 0) red[t >> 6] = s;
  __syncthreads();
  if (t == 0) enorm[c] = red[0] + red[1] + red[2] + red[3];
}

// ---------------------------------------------------------------------------
// Pre-split inputs into bf16 hi/lo, written tiled+XOR-swizzled so k_dist_fast
// can DMA them straight into LDS. Tile (rt, kc) = [128 rows][32 k], 8 KB.
__global__ __launch_bounds__(256) void k_asplit(const float* __restrict__ x,
                                                ushort_t* __restrict__ xhi,
                                                ushort_t* __restrict__ xlo) {
  int rt = blockIdx.x, t = threadIdx.x;
  int sr = t >> 1;            // row in tile 0..127
  int kh = (t & 1) << 4;      // k-half 0/16
  int s3 = sr & 3;
  const float* row = x + ((size_t)(rt << 7) + sr) * D_DIM + kh;
  size_t tb = (size_t)rt * 32768;  // 8 tiles * 4096 ushorts
#pragma unroll
  for (int kc = 0; kc < 8; ++kc) {
    float4 v0 = *(const float4*)(row + kc * 32 + 0);
    float4 v1 = *(const float4*)(row + kc * 32 + 4);
    float4 v2 = *(const float4*)(row + kc * 32 + 8);
    float4 v3 = *(const float4*)(row + kc * 32 + 12);
    uint4 h0, l0, h1, l1;
    split8(v0, v1, &h0, &l0);  // unit u0
    split8(v2, v3, &h1, &l1);  // unit u0+1
    int u0 = kh >> 3;
    size_t base = tb + (size_t)kc * 4096 + sr * 32;
    *(uint4*)&xhi[base + ((u0 ^ s3) << 3)] = h0;
    *(uint4*)&xhi[base + (((u0 + 1) ^ s3) << 3)] = h1;
    *(uint4*)&xlo[base + ((u0 ^ s3) << 3)] = l0;
    *(uint4*)&xlo[base + (((u0 + 1) ^ s3) << 3)] = l1;
  }
}

// ---------------------------------------------------------------------------
// Shared epilogue for both k_dist variants.
__device__ inline void dist_epilogue(f32x4 (&acc)[4][4], const float* __restrict__ enorm,
                                     float4* __restrict__ partials, float4 (*sRed)[128],
                                     int t, int wr, int wc, int lm, int quad,
                                     int rowBase, int colBase, int ct) {
  float enC[4]; int cidx[4];
#pragma unroll
  for (int j = 0; j < 4; ++j) {
    cidx[j] = colBase + (wc << 6) + (j << 4) + lm;
    enC[j] = enorm[cidx[j]];
  }
#pragma unroll
  for (int ti = 0; ti < 4; ++ti) {
#pragma unroll
    for (int reg = 0; reg < 4; ++reg) {
      float b0 = 3.0e38f, b1 = 3.0e38f;
      int i0 = 0x7fffffff, i1 = 0x7fffffff;
#pragma unroll
      for (int j = 0; j < 4; ++j) {
        float v = fmaf(-2.f, acc[ti][j][reg], enC[j]);
        int c = cidx[j];
        if (v < b0 || (v == b0 && c < i0)) { b1 = b0; i1 = i0; b0 = v; i0 = c; }
        else if (v < b1 || (v == b1 && c < i1)) { b1 = v; i1 = c; }
      }
      for (int m = 1; m < 16; m <<= 1) {
        float o0 = __shfl_xor(b0, m, 64); int oi0 = __shfl_xor(i0, m, 64);
        float o1 = __shfl_xor(b1, m, 64); int oi1 = __shfl_xor(i1, m, 64);
        merge2(b0, i0, b1, i1, o0, oi0, o1, oi1);
      }
      if (lm == 0) {
        int rloc = (wr << 6) + (ti << 4) + (quad << 2) + reg;
        sRed[wc][rloc] = make_float4(b0, (float)i0, b1, (float)i1);
      }
    }
  }
  __syncthreads();
  if (t < 128) {
    float4 p = sRed[0][t];
    float b0 = p.x; int i0 = (int)p.y; float b1 = p.z; int i1 = (int)p.w;
    float4 q = sRed[1][t];
    merge2(b0, i0, b1, i1, q.x, (int)q.y, q.z, (int)q.w);
    partials[(size_t)ct * M_ROWS + rowBase + t] = make_float4(b0, (float)i0, b1, (float)i1);
  }
}

// ---------------------------------------------------------------------------
// FAST: all 4 tiles DMA'd via global_load_lds from pre-split/pre-tiled arrays.
// XCD-aware swizzle: consecutive slots on one XCD = 8 col-tiles of one row-tile.
__global__ __launch_bounds__(256, 3) void k_dist_fast(const ushort_t* __restrict__ xhi,
                                                      const ushort_t* __restrict__ xlo,
                                                      const ushort_t* __restrict__ bhi,
                                                      const ushort_t* __restrict__ blo,
                                                      const float* __restrict__ enorm,
                                                      float4* __restrict__ partials) {
  __shared__ ushort_t sAhi[4096], sAlo[4096], sBhi[4096], sBlo[4096];
  __shared__ float4 sRed[2][128];

  int bx = blockIdx.x;
  int xcd = bx & 7, slot = bx >> 3;
  int rt = (xcd << 7) | (slot >> 3);
  int ct = slot & 7;
  int rowBase = rt << 7, colBase = ct << 7;
  int t = threadIdx.x;
  int w = t >> 6, lane = t & 63;
  int wr = w >> 1, wc = w & 1;
  int lm = lane & 15, quad = lane >> 4;

  f32x4 acc[4][4];
#pragma unroll
  for (int i = 0; i < 4; ++i)
#pragma unroll
    for (int j = 0; j < 4; ++j) acc[i][j] = (f32x4){0.f, 0.f, 0.f, 0.f};

  int aoff[4], boff[4];
#pragma unroll
  for (int ti = 0; ti < 4; ++ti) {
    int r = (wr << 6) + (ti << 4) + lm;
    aoff[ti] = r * 32 + ((quad ^ (r & 3)) << 3);
    int n = (wc << 6) + (ti << 4) + lm;
    boff[ti] = n * 32 + ((quad ^ (n & 3)) << 3);
  }

  // DMA chunk assignment: wave w copies 1KB chunks {2w, 2w+1} of each tile
  int c0 = w << 1;
  int src0 = c0 * 512 + lane * 8;  // ushort index; lane*16B
  const ushort_t* gA = xhi + (size_t)rt * 32768;
  const ushort_t* gAl = xlo + (size_t)rt * 32768;
  const ushort_t* gB = bhi + (size_t)ct * 32768;
  const ushort_t* gBl = blo + (size_t)ct * 32768;

  for (int kc = 0; kc < 8; ++kc) {
    int src = kc * 4096 + src0;
    gll16(gA + src, &sAhi[c0 * 512]);
    gll16(gA + src + 512, &sAhi[(c0 + 1) * 512]);
    gll16(gAl + src, &sAlo[c0 * 512]);
    gll16(gAl + src + 512, &sAlo[(c0 + 1) * 512]);
    gll16(gB + src, &sBhi[c0 * 512]);
    gll16(gB + src + 512, &sBhi[(c0 + 1) * 512]);
    gll16(gBl + src, &sBlo[c0 * 512]);
    gll16(gBl + src + 512, &sBlo[(c0 + 1) * 512]);
    __syncthreads();

    short8v ahi[4], bhi_f[4];
#pragma unroll
    for (int i = 0; i < 4; ++i) {
      ahi[i] = *(const short8v*)&sAhi[aoff[i]];
      bhi_f[i] = *(const short8v*)&sBhi[boff[i]];
    }
#pragma unroll
    for (int i = 0; i < 4; ++i)
#pragma unroll
      for (int j = 0; j < 4; ++j)
        acc[i][j] = __builtin_amdgcn_mfma_f32_16x16x32_bf16(ahi[i], bhi_f[j], acc[i][j], 0, 0, 0);
    short8v blo_f[4];
#pragma unroll
    for (int i = 0; i < 4; ++i) blo_f[i] = *(const short8v*)&sBlo[boff[i]];
#pragma unroll
    for (int i = 0; i < 4; ++i)
#pragma unroll
      for (int j = 0; j < 4; ++j)
        acc[i][j] = __builtin_amdgcn_mfma_f32_16x16x32_bf16(ahi[i], blo_f[j], acc[i][j], 0, 0, 0);
    short8v alo[4];
#pragma unroll
    for (int i = 0; i < 4; ++i) alo[i] = *(const short8v*)&sAlo[aoff[i]];
#pragma unroll
    for (int i = 0; i < 4; ++i)
#pragma unroll
      for (int j = 0; j < 4; ++j)
        acc[i][j] = __builtin_amdgcn_mfma_f32_16x16x32_bf16(alo[i], bhi_f[j], acc[i][j], 0, 0, 0);
    __syncthreads();
  }

  dist_epilogue(acc, enorm, partials, sRed, t, wr, wc, lm, quad, rowBase, colBase, ct);
}

// ---------------------------------------------------------------------------
// SLOW fallback (small ws): R2 structure, but cheap perm-based trunc split.
__global__ __launch_bounds__(256, 3) void k_dist_slow(const float* __restrict__ A,
                                                      const ushort_t* __restrict__ ehiT,
                                                      const ushort_t* __restrict__ eloT,
                                                      const float* __restrict__ enorm,
                                                      float4* __restrict__ partials) {
  __shared__ ushort_t sAhi[4096], sAlo[4096], sBhi[4096], sBlo[4096];
  __shared__ float4 sRed[2][128];

  int bx = blockIdx.x;
  int ct = bx & 7, rt = bx >> 3;
  int rowBase = rt << 7, colBase = ct << 7;
  int t = threadIdx.x;
  int w = t >> 6, lane = t & 63;
  int wr = w >> 1, wc = w & 1;
  int lm = lane & 15, quad = lane >> 4;
  int sr = t >> 1;
  int skh = (t & 1) << 4;

  f32x4 acc[4][4];
#pragma unroll
  for (int i = 0; i < 4; ++i)
#pragma unroll
    for (int j = 0; j < 4; ++j) acc[i][j] = (f32x4){0.f, 0.f, 0.f, 0.f};

  int aoff[4], boff[4];
#pragma unroll
  for (int ti = 0; ti < 4; ++ti) {
    int r = (wr << 6) + (ti << 4) + lm;
    aoff[ti] = r * 32 + ((quad ^ (r & 3)) << 3);
    int n = (wc << 6) + (ti << 4) + lm;
    boff[ti] = n * 32 + ((quad ^ (n & 3)) << 3);
  }

  const float* Arow = A + (size_t)(rowBase + sr) * D_DIM + skh;
  const ushort_t* Bhirow = ehiT + (size_t)(colBase + sr) * D_DIM + skh;
  const ushort_t* Blorow = eloT + (size_t)(colBase + sr) * D_DIM + skh;

  for (int kc = 0; kc < D_DIM; kc += 32) {
#pragma unroll
    for (int u = 0; u < 4; ++u) {
      float4 v = *(const float4*)(Arow + kc + (u << 2));
      int koff = skh + (u << 2);
      int dst = sr * 32 + (((koff >> 3) ^ (sr & 3)) << 3) + (koff & 7);
      *(uint2*)&sAhi[dst] = make_uint2(pack2(v.x, v.y), pack2(v.z, v.w));
      *(uint2*)&sAlo[dst] = make_uint2(pack2(rem1(v.x), rem1(v.y)), pack2(rem1(v.z), rem1(v.w)));
    }
#pragma unroll
    for (int h = 0; h < 2; ++h) {
      int koff = skh + (h << 3);
      int dst = sr * 32 + (((koff >> 3) ^ (sr & 3)) << 3);
      *(uint4*)&sBhi[dst] = *(const uint4*)(Bhirow + kc + (h << 3));
      *(uint4*)&sBlo[dst] = *(const uint4*)(Blorow + kc + (h << 3));
    }
    __syncthreads();

    short8v ahi[4], bhi_f[4], blo_f[4], alo[4];
#pragma unroll
    for (int i = 0; i < 4; ++i) {
      ahi[i] = *(const short8v*)&sAhi[aoff[i]];
      bhi_f[i] = *(const short8v*)&sBhi[boff[i]];
      blo_f[i] = *(const short8v*)&sBlo[boff[i]];
      alo[i] = *(const short8v*)&sAlo[aoff[i]];
    }
#pragma unroll
    for (int i = 0; i < 4; ++i)
#pragma unroll
      for (int j = 0; j < 4; ++j)
        acc[i][j] = __builtin_amdgcn_mfma_f32_16x16x32_bf16(ahi[i], bhi_f[j], acc[i][j], 0, 0, 0);
#pragma unroll
    for (int i = 0; i < 4; ++i)
#pragma unroll
      for (int j = 0; j < 4; ++j)
        acc[i][j] = __builtin_amdgcn_mfma_f32_16x16x32_bf16(ahi[i], blo_f[j], acc[i][j], 0, 0, 0);
#pragma unroll
    for (int i = 0; i < 4; ++i)
#pragma unroll
      for (int j = 0; j < 4; ++j)
        acc[i][j] = __builtin_amdgcn_mfma_f32_16x16x32_bf16(alo[i], bhi_f[j], acc[i][j], 0, 0, 0);
    __syncthreads();
  }

  dist_epilogue(acc, enorm, partials, sRed, t, wr, wc, lm, quad, rowBase, colBase, ct);
}

// ---------------------------------------------------------------------------
__global__ __launch_bounds__(256) void k_argmin(const float4* __restrict__ partials,
                                                int2* __restrict__ idx2) {
  int row = blockIdx.x * 256 + threadIdx.x;
  float b0 = 3.0e38f, b1 = 3.0e38f;
  int i0 = 0x7fffffff, i1 = 0x7fffffff;
#pragma unroll
  for (int tp = 0; tp < 8; ++tp) {
    float4 p = partials[(size_t)tp * M_ROWS + row];
    merge2(b0, i0, b1, i1, p.x, (int)p.y, p.z, (int)p.w);
  }
  idx2[row] = make_int2(i0, i1);
}

// ---------------------------------------------------------------------------
__global__ __launch_bounds__(256) void k_quant(const float* __restrict__ x,
                                               const float* __restrict__ embedT,
                                               const int2* __restrict__ idx2,
                                               float* __restrict__ outq,
                                               float* __restrict__ out_ind,
                                               int* __restrict__ counts,
                                               float* __restrict__ lossPart) {
  int b = blockIdx.x, t = threadIdx.x;
  int rl = t >> 6, lane = t & 63;
  float lsum = 0.f;
  __shared__ float red[4];
#pragma unroll
  for (int ri = 0; ri < 4; ++ri) {
    int row = b * 16 + ri * 4 + rl;
    int2 cc = idx2[row];
    float4 xv = *(const float4*)(x + (size_t)row * D_DIM + (lane << 2));
    float4 q0 = *(const float4*)(embedT + (size_t)cc.x * D_DIM + (lane << 2));
    float4 q1 = *(const float4*)(embedT + (size_t)cc.y * D_DIM + (lane << 2));
    float a0 = q0.x - xv.x, a1 = q0.y - xv.y, a2 = q0.z - xv.z, a3 = q0.w - xv.w;
    float c0 = q1.x - xv.x, c1 = q1.y - xv.y, c2 = q1.z - xv.z, c3 = q1.w - xv.w;
    float d0 = fmaf(a0, a0, fmaf(a1, a1, fmaf(a2, a2, a3 * a3)));
    float d1 = fmaf(c0, c0, fmaf(c1, c1, fmaf(c2, c2, c3 * c3)));
    for (int m = 1; m < 64; m <<= 1) {
      d0 += __shfl_xor(d0, m, 64);
      d1 += __shfl_xor(d1, m, 64);
    }
    bool sel = (d1 < d0) || (d1 == d0 && cc.y < cc.x);
    int widx = sel ? cc.y : cc.x;
    float4 qv;
    qv.x = sel ? q1.x : q0.x; qv.y = sel ? q1.y : q0.y;
    qv.z = sel ? q1.z : q0.z; qv.w = sel ? q1.w : q0.w;
    float4 o = make_float4(xv.x + (qv.x - xv.x), xv.y + (qv.y - xv.y),
                           xv.z + (qv.z - xv.z), xv.w + (qv.w - xv.w));
    *(float4*)(outq + (size_t)row * D_DIM + (lane << 2)) = o;
    lsum += sel ? d1 : d0;
    if (lane == 0) {
      out_ind[row] = (float)widx;
      atomicAdd(&counts[widx], 1);
    }
  }
  if (lane == 0) red[rl] = lsum;
  __syncthreads();
  if (t == 0) lossPart[b] = red[0] + red[1] + red[2] + red[3];
}

// ---------------------------------------------------------------------------
__global__ __launch_bounds__(1024) void k_final(const int* __restrict__ counts,
                                                const float* __restrict__ lossPart,
                                                float* __restrict__ out_scalars) {
  int t = threadIdx.x;
  double ls = 0.0;
#pragma unroll
  for (int u = 0; u < 8; ++u) ls += (double)lossPart[t * 8 + u];
  float p = (float)counts[t] * (1.0f / (float)M_ROWS);
  float ent = p * logf(p + 1e-10f);
  double lred = ls;
  float ered = ent;
  for (int off = 32; off > 0; off >>= 1) {
    lred += __shfl_down(lred, off, 64);
    ered += __shfl_down(ered, off, 64);
  }
  __shared__ double lsh[16];
  __shared__ float esh[16];
  int w = t >> 6;
  if ((t & 63) == 0) { lsh[w] = lred; esh[w] = ered; }
  __syncthreads();
  if (t == 0) {
    double L = 0.0;
    float E = 0.f;
    for (int i = 0; i < 16; ++i) { L += lsh[i]; E += esh[i]; }
    out_scalars[0] = (float)(L / (double)QELEMS);
    out_scalars[1] = expf(-E);
  }
}

// ---------------------------------------------------------------------------
extern "C" void kernel_launch(void* const* d_in, const int* in_sizes, int n_in,
                              void* d_out, int out_size, void* d_ws, size_t ws_size,
                              hipStream_t stream) {
  const float* inputs = (const float*)d_in[0];  // [131072,256]
  const float* embed = (const float*)d_in[1];   // [256,1024]
  float* out = (float*)d_out;
  char* ws = (char*)d_ws;
  float* embedT = (float*)(ws + WS_EMBEDT);
  ushort_t* b1 = (ushort_t*)(ws + WS_B1);
  ushort_t* b2 = (ushort_t*)(ws + WS_B2);
  float* enorm = (float*)(ws + WS_ENORM);
  float4* partials = (float4*)(ws + WS_PART);
  int2* idx2 = (int2*)(ws + WS_IDX2);
  int* counts = (int*)(ws + WS_COUNTS);
  float* lossPart = (float*)(ws + WS_LOSSP);
  ushort_t* xhi = (ushort_t*)(ws + WS_XHI);
  ushort_t* xlo = (ushort_t*)(ws + WS_XLO);

  int fast = (ws_size >= (size_t)WS_FAST_TOTAL) ? 1 : 0;

  hipMemsetAsync(counts, 0, NCODES * sizeof(int), stream);
  k_prep<<<NCODES, 256, 0, stream>>>(embed, embedT, b1, b2, enorm, fast);
  if (fast) {
    k_asplit<<<M_ROWS / 128, 256, 0, stream>>>(inputs, xhi, xlo);
    k_dist_fast<<<8192, 256, 0, stream>>>(xhi, xlo, b1, b2, enorm, partials);
  } else {
    k_dist_slow<<<8192, 256, 0, stream>>>(inputs, b1, b2, enorm, partials);
  }
  k_argmin<<<M_ROWS / 256, 256, 0, stream>>>(partials, idx2);
  k_quant<<<8192, 256, 0, stream>>>(inputs, embedT, idx2, out, out + QELEMS + 2,
                                    counts, lossPart);
  k_final<<<1, 1024, 0, stream>>>(counts, lossPart, out + QELEMS);
}